// Round 2
// baseline (278.631 us; speedup 1.0000x reference)
//
#include <hip/hip_runtime.h>

// CTC batch cost, linear-domain, single wave per batch element, DIAGONAL SKEW.
// ROUND 2 restructure: skew deepened to G=4 (lane L owns states 4L..4L+3 and
// at wave-step n computes t = n - 4L). Rationale (r1 post-mortem): per-step
// time was pinned at ~286cy regardless of prob-read prefetch -> the stall is
// lgkmcnt waiting, and the tightest consumer was the 2-step-slack __shfl_up.
// With G=4:
//   - halo a3 (left's step n-5) is consumed at step n -> 5-step shuffle slack
//   - e changes only at renorms (every 4 steps, globally aligned) -> shuffle
//     e once per 4-step block, not per step (1.25 bpermute/step, was 2)
//   - dormant-lane exponent adoption moves into the renorm (-5 VALU/step)
//   - all DS consumers now tolerate an imprecise lgkmcnt(15): at ~5.5
//     DS-ops/step that waits only for ops >=3 steps old (>=360cy >> 120cy
//     LDS latency) -> no stall even without precise counting
// Cost: 200 extra drain steps (NTOT=1223) and NSLOT 128->256 (LDS 135KB,
// still 1 block/CU like before).
//
// Bank fix under G=4: the blank-prob read (same class, rows stepping 4/lane)
// would be 16-way conflicted in rowbuf (4*130 = 8 mod 32 -> 4 banks). Blank
// probs are staged into blkbuf with index ((r&3)<<6)|((r>>2)&63): lane-to-
// lane word step 1 -> conflict-free. Label-class reads are random-banked.
//
// Exactness: consumed (a3, e) pairs are the same (value, exponent) pairs the
// old scheme shuffled (same renorm cadence, post-renorm stash at phase 3);
// all scaling is by powers of two -> bit-identical alphas, absmax 0.0.
//
// Recurrence (unchanged, absmax 0.0 lineage):
//   n0 = (a0 + h1) * pb
//   n1 = (a1 + a0 + ms1*h1) * p_lab0
//   n2 = (a2 + a1) * pb
//   n3 = (a3 + a2 + ms3*a1) * p_lab1
// with per-lane exponent e (true alpha = a*2^e), renorm every 4 steps.

#define Bc 256
#define Tc 1024
#define Cc 128
#define Uc 100
#define BLANKc 127
#define EPSc 1e-7f
#define LN2f 0.69314718055994530942f
#define RSTRIDE 130          // floats per row slot (even -> 8B-aligned float2)
#define NSLOT 256            // circular depth (live window ~216 rows at G=4)
#define QD 8                 // global->LDS staging queue depth
#define PF 8                 // prob-gather prefetch distance (wave-steps)
#define NTOT 1223            // lane 50 finishes t=1023 at n = 1023 + 4*50

__global__ __launch_bounds__(64) void ctc_skew_kernel(
    const float* __restrict__ y_pred,     // [B,T,C] post-softmax probs
    const int*   __restrict__ y_true,     // [B,U]
    const int*   __restrict__ label_len,  // [B]
    float*       __restrict__ out)        // [B,1]
{
    __shared__ float rowbuf[NSLOT * RSTRIDE];   // 133120 B circular row cache
    __shared__ float blkbuf[NSLOT];             // blank prob per row, bank-spread
    __shared__ float shA[204];
    __shared__ int   shE[64];

    const int b     = blockIdx.x;
    const int lane  = threadIdx.x;                 // 0..63
    const int lane4 = lane * 4;
    const float* gp = y_pred + (size_t)b * (Tc * Cc);

    // ---- per-lane label classes & skip masks (time-invariant) ----
    const int k0  = 2*lane, k1 = 2*lane+1;
    const int k0c = k0 < Uc ? k0 : Uc-1;
    const int k1c = k1 < Uc ? k1 : Uc-1;
    const int y0  = y_true[b*Uc + k0c];            // class of state 4L+1
    const int y1  = y_true[b*Uc + k1c];            // class of state 4L+3
    int ym1 = y0;
    if (lane > 0) ym1 = y_true[b*Uc + k0 - 1];
    const float ms1 = (lane > 0 && y0 != ym1) ? 1.0f : 0.0f;
    const float ms3 = (y1 != y0) ? 1.0f : 0.0f;
    const float mh  = (lane > 0) ? 1.0f : 0.0f;    // lane 0 has no left halo

    // ---- t=0 init (only lane 0 holds mass) ----
    float a0=0.f, a1=0.f, a2=0.f, a3=0.f;
    if (lane == 0) { a0 = gp[BLANKc]+EPSc; a1 = gp[y0]+EPSc; }
    int e = 0;

    // ---- pre-stage rows 0..15 into LDS (coalesced float4 reads) ----
#pragma unroll
    for (int i = 0; i < 8; ++i) {
        const int f4  = i*64 + lane;               // 512 float4 across 16 rows
        const int row = f4 >> 5;                   // 32 float4 per row
        const int c4  = (f4 & 31) * 4;
        const float4 v = *(const float4*)(gp + row*Cc + c4);
        float* dst = &rowbuf[row*RSTRIDE + c4];
        dst[0]=v.x; dst[1]=v.y; dst[2]=v.z; dst[3]=v.w;
    }
    // single wave: LDS writes/reads are program-ordered; no barrier needed.
    if (lane < 16)
        blkbuf[((lane & 3) << 6) | ((lane >> 2) & 63)] =
            rowbuf[lane*RSTRIDE + BLANKc];

    // ---- staging queue: rows 16..23 in flight ----
    float2 Q[QD];
#pragma unroll
    for (int k = 0; k < QD; ++k)
        Q[k] = *(const float2*)(gp + (16+k)*Cc + lane*2);

    // ---- prob prefetch: PQ[k] holds step n=k+1's probs (row n-4L, clamped)
    float PQb[PF], PQ0[PF], PQ1[PF];
#pragma unroll
    for (int k = 0; k < PF; ++k) {
        int rr = (k+1) - lane4; rr = rr < 0 ? 0 : rr;
        const float* rp = &rowbuf[(rr & (NSLOT-1)) * RSTRIDE];
        PQ0[k] = rp[y0]; PQ1[k] = rp[y1];
        PQb[k] = blkbuf[((rr & 3) << 6) | ((rr >> 2) & 63)];
    }

    // ---- halo rings: HQ written at step p, read at p+5; ER per-block ----
    float HQ[8] = {0,0,0,0,0,0,0,0};
    int   ER[2] = {0,0};
    float hscale = mh;
    int   el_blk = 0;
    int   rbase  = PF - lane4;    // pre-incremented -> n+PF-4*lane

    auto body = [&](int n, int j, bool fzp) {
        const int qi = j & 7;                      // == (n-1)&7 (n = 16c+j+1)
        // -- block top (phase 0): batch exponent & halo scale, 5-step slack
        if ((j & 3) == 0) {
            el_blk = ER[(j >> 2) & 1];             // left e paired with batch
            int d = el_blk - e; d = d > 126 ? 126 : d;
            hscale = ldexpf(mh, d);                // exact pow2 (0 for lane 0)
        }
        // -- this step's probs (gathered PF=8 steps ago) --
        const float pb = PQb[qi] + EPSc;
        const float p0 = PQ0[qi] + EPSc;
        const float p1 = PQ1[qi] + EPSc;
        // -- refill PQ slot with step n+8's gathers --
        rbase += 1;                                // = n+8-4*lane
        int rcl = rbase; rcl = rcl < 0 ? 0 : rcl; rcl = rcl > Tc-1 ? Tc-1 : rcl;
        {
            const float* rp = &rowbuf[(rcl & (NSLOT-1)) * RSTRIDE];
            PQ0[qi] = rp[y0];
            PQ1[qi] = rp[y1];
            PQb[qi] = blkbuf[((rcl & 3) << 6) | ((rcl >> 2) & 63)];
        }
        // -- stage row n+15 (loaded 8 steps ago), reload row n+23 --
        {
            const int ws = (n + 15) & (NSLOT-1);
            *(float2*)&rowbuf[ws * RSTRIDE + lane*2] = Q[qi];
            if (lane == 63) {                      // lane 63 holds cls 126/127
                const int wb = n + 15;
                blkbuf[((wb & 3) << 6) | ((wb >> 2) & 63)] = Q[qi].y;
            }
            int lr = n + 23; lr = lr > Tc-1 ? Tc-1 : lr;
            Q[qi] = *(const float2*)(gp + lr*Cc + lane*2);
        }
        // -- halo from left's step n-5 = A[4L-1](t-1), 5-step slack --
        const float h1 = HQ[(j + 3) & 7] * hscale;
        const float n0 = (a0 + h1) * pb;
        const float n1 = (a1 + a0 + ms1*h1) * p0;
        const float n2 = (a2 + a1) * pb;
        const float n3 = (a3 + a2 + ms3*a1) * p1;
        bool upd = true;
        if (fzp) upd = (lane4 >= n - (Tc-1));      // freeze lanes past t=1023
        if (upd) { a0=n0; a1=n1; a2=n2; a3=n3; }
        // -- renorm + dormant-lane e adoption (phase 3) --
        if ((j & 3) == 3) {
            const float m = fmaxf(fmaxf(a0,a1), fmaxf(a2,a3));
            int ex = (int)((__float_as_uint(m) >> 23) & 0xFF) - 127;
            ex = (m > 0.0f) ? ex : (el_blk - e);   // dormant: e := el_blk
            a0 = ldexpf(a0,-ex); a1 = ldexpf(a1,-ex);
            a2 = ldexpf(a2,-ex); a3 = ldexpf(a3,-ex);
            e += ex;
        }
        // -- halo out: a3 every step (post-renorm on phase 3), e per block --
        HQ[j & 7] = __shfl_up(a3, 1, 64);
        if ((j & 3) == 3) ER[(j >> 2) & 1] = __shfl_up(e, 1, 64);
    };

    // ---- wave-steps n = 1..1223 ----
    int n = 1;
    for (int c = 0; c < 63; ++c) {                 // n = 1..1008: no freeze
#pragma unroll
        for (int j = 0; j < 16; ++j) { body(n, j, false); ++n; }
    }
    for (int c = 0; c < 13; ++c) {                 // n = 1009..1216 (freeze
#pragma unroll                                     //  predicate inert <1024)
        for (int j = 0; j < 16; ++j) { body(n, j, true); ++n; }
    }
#pragma unroll
    for (int j = 0; j < 7; ++j) { body(n, j, true); ++n; }   // n = 1217..1223

    // ---- epilogue: loss = -ln( A[2L-1] + A[2L] ), A = a * 2^e ----
    if (lane < 51) {
        shA[4*lane+0] = a0; shA[4*lane+1] = a1;
        shA[4*lane+2] = a2; shA[4*lane+3] = a3;
        shE[lane] = e;
    }
    __syncthreads();                               // one-time, post-loop
    if (lane == 0) {
        const int L  = label_len[b];
        const int s1 = 2*L - 1, s2 = 2*L;
        const float v1 = shA[s1], v2 = shA[s2];
        const int   e1 = shE[s1 >> 2], e2 = shE[s2 >> 2];
        const int   em = e1 > e2 ? e1 : e2;
        const float sum = ldexpf(v1, e1-em) + ldexpf(v2, e2-em);
        const float r   = __log2f(sum) + (float)em;
        out[b] = -LN2f * r;
    }
}

extern "C" void kernel_launch(void* const* d_in, const int* in_sizes, int n_in,
                              void* d_out, int out_size, void* d_ws, size_t ws_size,
                              hipStream_t stream) {
    const float* y_pred    = (const float*)d_in[0];
    const int*   y_true    = (const int*)d_in[1];
    const int*   label_len = (const int*)d_in[2];
    float*       out       = (float*)d_out;
    ctc_skew_kernel<<<Bc, 64, 0, stream>>>(y_pred, y_true, label_len, out);
}